// Round 2
// baseline (323.393 us; speedup 1.0000x reference)
//
#include <hip/hip_runtime.h>

#define NODES 4096

typedef float f32x4 __attribute__((ext_vector_type(4)));
typedef float f32x8 __attribute__((ext_vector_type(8)));
typedef __bf16 bf16x8 __attribute__((ext_vector_type(8)));
typedef unsigned short u16x8 __attribute__((ext_vector_type(8)));
typedef unsigned short u16x4 __attribute__((ext_vector_type(4)));

__device__ __forceinline__ unsigned short f2bf(float x) {
    unsigned u = __builtin_bit_cast(unsigned, x);
    return (unsigned short)((u + 0x7fffu + ((u >> 16) & 1u)) >> 16);
}

// ---- stage A: h = tanh(x@Wm + bm), stored transposed bf16 [64][4096] -------
__global__ __launch_bounds__(256) void prep_h(
    const float* __restrict__ f0, const float* __restrict__ f1,
    const float* __restrict__ Wm0, const float* __restrict__ bm0,
    const float* __restrict__ Wm1, const float* __restrict__ bm1,
    unsigned short* __restrict__ hT0, unsigned short* __restrict__ hT1)
{
    const int d = threadIdx.x & 63;
    int n = blockIdx.x * 4 + (threadIdx.x >> 6);
    n = __builtin_amdgcn_readfirstlane(n);   // wave-uniform -> s_loads of the feature row
    const float* r0 = f0 + (size_t)n * 256;
    float a0 = bm0[d];
#pragma unroll 8
    for (int k = 0; k < 256; ++k) a0 = fmaf(r0[k], Wm0[k * 64 + d], a0);
    hT0[(size_t)d * NODES + n] = f2bf(tanhf(a0));
    const float* r1 = f1 + (size_t)n * 128;
    float a1 = bm1[d];
#pragma unroll 8
    for (int k = 0; k < 128; ++k) a1 = fmaf(r1[k], Wm1[k * 64 + d], a1);
    hT1[(size_t)d * NODES + n] = f2bf(tanhf(a1));
}

// ---- adjacency GEMM, barrier-free k-loop --------------------------------
// Each wave owns 16 rows x 64 cols over a private K-chunk (K-split across the
// block's 4 waves). A fragments loaded straight from global (f32 -> bf16 in
// register), B fragments straight from L2-resident hT. Depth-2 pipeline, no
// __syncthreads in the loop; one LDS reduction at the end.
// Fragment map (verified round 1): lane=(fr,fg), A[row0+fr][k+fg*8..+8],
// B = hT[c*16+fr][same k], acc[c][j] -> C[row0+fg*4+j][c*16+fr].
__global__ __launch_bounds__(256, 5) void adj_gemm(
    const float* __restrict__ A0, const float* __restrict__ A1,
    const float* __restrict__ A2, const float* __restrict__ A3,
    const float* __restrict__ A4,
    const unsigned short* __restrict__ hTa, const unsigned short* __restrict__ hTb,
    int split, float* __restrict__ outBase, unsigned tanhMask,
    int rgShift, int kcw)
{
    __shared__ float red[3][64][20];   // +4 pad: breaks 64B-stride bank conflict

    const int job = blockIdx.y;
    const float* adj = job == 0 ? A0 : job == 1 ? A1 : job == 2 ? A2 : job == 3 ? A3 : A4;
    const unsigned short* hT = (job < split) ? hTa : hTb;
    const bool doTanh = (tanhMask >> job) & 1u;

    const int bx = blockIdx.x;
    const int rg = bx >> rgShift;
    const int kh = bx & ((1 << rgShift) - 1);
    const int row0 = rg * 16;
    const int lane = threadIdx.x & 63;
    const int wid = threadIdx.x >> 6;
    const int fr = lane & 15, fg = lane >> 4;
    const int kbeg = kh * (kcw * 4) + wid * kcw;
    const int nkt = kcw >> 5;                      // k-tiles of 32 per wave

    const char* aB = (const char*)adj;
    const char* hB = (const char*)hT;
    unsigned aoff = (unsigned)(((row0 + fr) * NODES + kbeg + fg * 8) * 4);
    unsigned boff = (unsigned)((fr * NODES + kbeg + fg * 8) * 2);
    const unsigned bstep = NODES * 32u;            // 16 rows * 4096 * 2B

    f32x8 aN = *(const f32x8*)(aB + aoff);
    u16x8 bN0 = *(const u16x8*)(hB + boff);
    u16x8 bN1 = *(const u16x8*)(hB + boff + bstep);
    u16x8 bN2 = *(const u16x8*)(hB + boff + 2 * bstep);
    u16x8 bN3 = *(const u16x8*)(hB + boff + 3 * bstep);
    aoff += 128; boff += 64;

    f32x4 acc0 = {0.f,0.f,0.f,0.f}, acc1 = {0.f,0.f,0.f,0.f};
    f32x4 acc2 = {0.f,0.f,0.f,0.f}, acc3 = {0.f,0.f,0.f,0.f};

    for (int kt = 0; kt < nkt; ++kt) {
        f32x8 aC = aN;
        u16x8 b0 = bN0, b1 = bN1, b2 = bN2, b3 = bN3;
        if (kt + 1 < nkt) {                         // issue next tile's loads early
            aN  = *(const f32x8*)(aB + aoff);
            bN0 = *(const u16x8*)(hB + boff);
            bN1 = *(const u16x8*)(hB + boff + bstep);
            bN2 = *(const u16x8*)(hB + boff + 2 * bstep);
            bN3 = *(const u16x8*)(hB + boff + 3 * bstep);
            aoff += 128; boff += 64;
        }
        bf16x8 af = __builtin_convertvector(aC, bf16x8);
        acc0 = __builtin_amdgcn_mfma_f32_16x16x32_bf16(af, __builtin_bit_cast(bf16x8, b0), acc0, 0, 0, 0);
        acc1 = __builtin_amdgcn_mfma_f32_16x16x32_bf16(af, __builtin_bit_cast(bf16x8, b1), acc1, 0, 0, 0);
        acc2 = __builtin_amdgcn_mfma_f32_16x16x32_bf16(af, __builtin_bit_cast(bf16x8, b2), acc2, 0, 0, 0);
        acc3 = __builtin_amdgcn_mfma_f32_16x16x32_bf16(af, __builtin_bit_cast(bf16x8, b3), acc3, 0, 0, 0);
    }

    if (wid) {
        float* r = &red[wid - 1][lane][0];
        *(f32x4*)(r + 0)  = acc0; *(f32x4*)(r + 4)  = acc1;
        *(f32x4*)(r + 8)  = acc2; *(f32x4*)(r + 12) = acc3;
    }
    __syncthreads();
    if (wid == 0) {
#pragma unroll
        for (int w = 0; w < 3; ++w) {
            const float* r = &red[w][lane][0];
            acc0 += *(const f32x4*)(r + 0);  acc1 += *(const f32x4*)(r + 4);
            acc2 += *(const f32x4*)(r + 8);  acc3 += *(const f32x4*)(r + 12);
        }
        float* C = outBase + (size_t)((job << rgShift) | kh) * (NODES * 64);
        float* Cw = C + (size_t)(row0 + fg * 4) * 64 + fr;
#pragma unroll
        for (int j = 0; j < 4; ++j) {
            float v0 = acc0[j], v1 = acc1[j], v2 = acc2[j], v3 = acc3[j];
            if (doTanh) { v0 = tanhf(v0); v1 = tanhf(v1); v2 = tanhf(v2); v3 = tanhf(v3); }
            Cw[j * 64 + 0]  = v0; Cw[j * 64 + 16] = v1;
            Cw[j * 64 + 32] = v2; Cw[j * 64 + 48] = v3;
        }
    }
}

// ---- stage C: semantic-attention logits (atomic) + schema softmax -> iccT bf16 [64][4096]
__global__ __launch_bounds__(128) void stage_c(
    const float* __restrict__ agg, const float* __restrict__ Wa,
    const float* __restrict__ ba, const float* __restrict__ qa,
    const float* __restrict__ wsv, float* __restrict__ sacc,
    unsigned short* __restrict__ iccT)
{
    const int n = blockIdx.x;
    const int p = threadIdx.x;          // 0..127 = PROJ lanes
    __shared__ float rs[3][2];
    __shared__ float ru[2][2];

    const float* h0p = agg + (size_t)n * 64;                       // hr[0]
    const float* h1p = agg + ((size_t)NODES + n) * 64;             // hr[1]
    const float* h2p = agg + ((size_t)2 * NODES + n) * 64;         // hr[2]
    float a0 = ba[p], a1 = a0, a2 = a0;
#pragma unroll 8
    for (int d = 0; d < 64; ++d) {
        float w = Wa[d * 128 + p];
        a0 = fmaf(h0p[d], w, a0);
        a1 = fmaf(h1p[d], w, a1);
        a2 = fmaf(h2p[d], w, a2);
    }
    float qv = qa[p];
    float v0 = tanhf(a0) * qv, v1 = tanhf(a1) * qv, v2 = tanhf(a2) * qv;

    const float* z0 = agg + ((size_t)3 * NODES + n) * 64;          // zk[0]
    const float* z1 = agg + ((size_t)4 * NODES + n) * 64;          // zk[1]
    float u0 = (p < 64) ? z0[p] * wsv[p] : 0.f;
    float u1 = (p < 64) ? z1[p] * wsv[p] : 0.f;

#pragma unroll
    for (int off = 32; off; off >>= 1) {
        v0 += __shfl_down(v0, off); v1 += __shfl_down(v1, off); v2 += __shfl_down(v2, off);
        u0 += __shfl_down(u0, off); u1 += __shfl_down(u1, off);
    }
    if ((p & 63) == 0) {
        int w = p >> 6;
        rs[0][w] = v0; rs[1][w] = v1; rs[2][w] = v2;
        ru[0][w] = u0; ru[1][w] = u1;
    }
    __syncthreads();
    if (p < 3) atomicAdd(&sacc[p], rs[p][0] + rs[p][1]);

    float U0 = ru[0][0] + ru[0][1];
    float U1 = ru[1][0] + ru[1][1];
    float mx = fmaxf(U0, U1);
    float e0 = expf(U0 - mx), e1 = expf(U1 - mx);
    float inv = 1.f / (e0 + e1);
    if (p < 64) {
        float icc = (e0 * z0[p] + e1 * z1[p]) * inv;
        iccT[(size_t)p * NODES + n] = f2bf(icc);
    }
}

// ---- stage E: relation_agg, item-item attention, AggAttention, projection ----
// ymp holds 4 partial sums: [job0 kh0][job0 kh1][job1 kh0][job1 kh1]; we do
// ym[m] = tanh(partial_a + partial_b) here.
__global__ __launch_bounds__(256) void finalize(
    const float* __restrict__ agg, const float* __restrict__ ymp,
    const float* __restrict__ sacc,
    const float* __restrict__ Wc1, const float* __restrict__ bc1, const float* __restrict__ wc2,
    const float* __restrict__ Wt1, const float* __restrict__ bt1, const float* __restrict__ wt2,
    const float* __restrict__ Wp, const float* __restrict__ bp,
    float* __restrict__ out)
{
    __shared__ float sWc[64 * 128];
    __shared__ float sWp[64 * 16];
    __shared__ float sY0[2][64], sY1[2][64];
    __shared__ float sHs0[2][64], sHs1[2][64], sHv[2][64];
    __shared__ float rA[2][2], rB[2][2];

    const int t = threadIdx.x;
    for (int i = t; i < 64 * 128; i += 256) sWc[i] = Wc1[i];
    for (int i = t; i < 64 * 16; i += 256) sWp[i] = Wp[i];

    float s0 = sacc[0] * (1.f / NODES), s1 = sacc[1] * (1.f / NODES), s2 = sacc[2] * (1.f / NODES);
    float sm = fmaxf(s0, fmaxf(s1, s2));
    float b0 = expf(s0 - sm), b1 = expf(s1 - sm), b2 = expf(s2 - sm);
    float bi = 1.f / (b0 + b1 + b2);
    b0 *= bi; b1 *= bi; b2 *= bi;

    const int sub = t >> 7;       // 2 nodes processed in parallel
    const int p = t & 127;
    const int wiH = p >> 6;
    const float bcv = bc1[p], wcv = wc2[p], btv = bt1[p], wtv = wt2[p];
    __syncthreads();

    for (int it = 0; it < 8; ++it) {
        const int n = blockIdx.x * 16 + it * 2 + sub;
        if (p < 64) {
            const size_t NN64 = (size_t)NODES * 64;
            float ya = ymp[(size_t)n * 64 + p]          + ymp[NN64 + (size_t)n * 64 + p];
            float yb = ymp[2 * NN64 + (size_t)n * 64 + p] + ymp[3 * NN64 + (size_t)n * 64 + p];
            sY0[sub][p] = tanhf(ya);
            sY1[sub][p] = tanhf(yb);
            sHs0[sub][p] = b0 * agg[(size_t)n * 64 + p]
                         + b1 * agg[((size_t)NODES + n) * 64 + p]
                         + b2 * agg[((size_t)2 * NODES + n) * 64 + p];
        }
        __syncthreads();
        float ac0 = bcv, ac1 = bcv;
#pragma unroll 8
        for (int d = 0; d < 64; ++d) {
            float w = sWc[d * 128 + p];
            ac0 = fmaf(sY0[sub][d], w, ac0);
            ac1 = fmaf(sY1[sub][d], w, ac1);
        }
        float v0 = tanhf(ac0) * wcv, v1 = tanhf(ac1) * wcv;
#pragma unroll
        for (int off = 32; off; off >>= 1) { v0 += __shfl_down(v0, off); v1 += __shfl_down(v1, off); }
        if ((p & 63) == 0) { rA[sub][wiH] = v0; rB[sub][wiH] = v1; }
        __syncthreads();
        float wm0 = rA[sub][0] + rA[sub][1];
        float wm1 = rB[sub][0] + rB[sub][1];
        float mm = fmaxf(wm0, wm1);
        float g0 = expf(wm0 - mm), g1 = expf(wm1 - mm);
        float gi = 1.f / (g0 + g1);
        g0 *= gi; g1 *= gi;
        if (p < 64) sHs1[sub][p] = g0 * sY0[sub][p] + g1 * sY1[sub][p];
        __syncthreads();

        float at0 = btv, at1 = btv;
#pragma unroll 8
        for (int d = 0; d < 64; ++d) {
            float w = Wt1[d * 128 + p];
            at0 = fmaf(sHs0[sub][d], w, at0);
            at1 = fmaf(sHs1[sub][d], w, at1);
        }
        float q0 = tanhf(at0) * wtv, q1 = tanhf(at1) * wtv;
#pragma unroll
        for (int off = 32; off; off >>= 1) { q0 += __shfl_down(q0, off); q1 += __shfl_down(q1, off); }
        if ((p & 63) == 0) { rA[sub][wiH] = q0; rB[sub][wiH] = q1; }
        __syncthreads();
        float t0 = rA[sub][0] + rA[sub][1];
        float t1 = rB[sub][0] + rB[sub][1];
        float tm = fmaxf(t0, t1);
        float c0 = expf(t0 - tm), c1 = expf(t1 - tm);
        float ci = 1.f / (c0 + c1);
        c0 *= ci; c1 *= ci;
        if (p < 64) {
            float H = c0 * sHs0[sub][p] + c1 * sHs1[sub][p];
            sHv[sub][p] = H;
            out[(size_t)NODES * 16 + (size_t)n * 64 + p] = H;
        }
        __syncthreads();
        if (p < 16) {
            float a = bp[p];
#pragma unroll 8
            for (int d = 0; d < 64; ++d) a = fmaf(sHv[sub][d], sWp[d * 16 + p], a);
            out[(size_t)n * 16 + p] = a;
        }
        __syncthreads();
    }
}

extern "C" void kernel_launch(void* const* d_in, const int* in_sizes, int n_in,
                              void* d_out, int out_size, void* d_ws, size_t ws_size,
                              hipStream_t stream)
{
    const float* f0   = (const float*)d_in[0];
    const float* f1   = (const float*)d_in[1];
    const float* adjS = (const float*)d_in[2];
    const float* adjM = (const float*)d_in[3];
    const float* adjK = (const float*)d_in[4];
    const float* Wm0  = (const float*)d_in[5];
    const float* bm0  = (const float*)d_in[6];
    const float* Wm1  = (const float*)d_in[7];
    const float* bm1  = (const float*)d_in[8];
    const float* Wa   = (const float*)d_in[9];
    const float* ba   = (const float*)d_in[10];
    const float* qa   = (const float*)d_in[11];
    const float* wsv  = (const float*)d_in[12];
    const float* Wc1  = (const float*)d_in[13];
    const float* bc1  = (const float*)d_in[14];
    const float* wc2  = (const float*)d_in[15];
    const float* Wt1  = (const float*)d_in[16];
    const float* bt1  = (const float*)d_in[17];
    const float* wt2  = (const float*)d_in[18];
    const float* Wp   = (const float*)d_in[19];
    const float* bpv  = (const float*)d_in[20];
    float* out = (float*)d_out;

    // workspace layout (bytes) — total 8,912,960 B, identical footprint to round 1:
    //   0        hT0   512 KB
    //   524288   hT1   512 KB
    //   1048576  iccT  512 KB
    //   1572864  agg   5 MB   (slots s0..s4, 1 MB each)
    //   4718592  ymp   4 MB   (overlays dead s3,s4 + 2 MB fresh)
    //   8912896  sacc  64 B
    char* ws = (char*)d_ws;
    unsigned short* hT0  = (unsigned short*)(ws);
    unsigned short* hT1  = (unsigned short*)(ws + 524288);
    unsigned short* iccT = (unsigned short*)(ws + 1048576);
    float* agg           = (float*)(ws + 1572864);
    float* ymp           = (float*)(ws + 4718592);
    float* sacc          = (float*)(ws + 8912896);

    hipMemsetAsync(sacc, 0, 64, stream);
    prep_h<<<dim3(1024), dim3(256), 0, stream>>>(f0, f1, Wm0, bm0, Wm1, bm1, hT0, hT1);

    const size_t NNs = (size_t)NODES * NODES;
    // jobs: hr[0..2] = tanh(adj_meta[r] @ h0), zk[0..1] = adj_schema[k] @ h1
    adj_gemm<<<dim3(256, 5), dim3(256), 0, stream>>>(
        adjM, adjM + NNs, adjM + 2 * NNs, adjK, adjK + NNs,
        hT0, hT1, 3, agg, 0x7u, 0, 1024);
    stage_c<<<dim3(4096), dim3(128), 0, stream>>>(agg, Wa, ba, qa, wsv, sacc, iccT);
    // ym partials: [job][khalf] = adj_same[job][:, khalf*2048:+2048] @ icc (no tanh here)
    adj_gemm<<<dim3(512, 2), dim3(256), 0, stream>>>(
        adjS, adjS + NNs, adjS, adjS, adjS,
        iccT, iccT, 5, ymp, 0x0u, 1, 512);
    finalize<<<dim3(256), dim3(256), 0, stream>>>(
        agg, ymp, sacc, Wc1, bc1, wc2, Wt1, bt1, wt2, Wp, bpv, out);
}

// Round 3
// 299.076 us; speedup vs baseline: 1.0813x; 1.0813x over previous
//
#include <hip/hip_runtime.h>

#define NODES 4096

typedef float f32x4 __attribute__((ext_vector_type(4)));
typedef float f32x8 __attribute__((ext_vector_type(8)));
typedef __bf16 bf16x8 __attribute__((ext_vector_type(8)));
typedef unsigned short u16x8 __attribute__((ext_vector_type(8)));

__device__ __forceinline__ unsigned short f2bf(float x) {
    unsigned u = __builtin_bit_cast(unsigned, x);
    return (unsigned short)((u + 0x7fffu + ((u >> 16) & 1u)) >> 16);
}

__device__ __forceinline__ void glds16(const void* g, void* l) {
    __builtin_amdgcn_global_load_lds(
        (const __attribute__((address_space(1))) unsigned int*)g,
        (__attribute__((address_space(3))) unsigned int*)l,
        16, 0, 0);
}

// ---- stage A: h = tanh(x@Wm + bm), stored transposed bf16 [64][4096] -------
__global__ __launch_bounds__(256) void prep_h(
    const float* __restrict__ f0, const float* __restrict__ f1,
    const float* __restrict__ Wm0, const float* __restrict__ bm0,
    const float* __restrict__ Wm1, const float* __restrict__ bm1,
    unsigned short* __restrict__ hT0, unsigned short* __restrict__ hT1)
{
    const int d = threadIdx.x & 63;
    int n = blockIdx.x * 4 + (threadIdx.x >> 6);
    n = __builtin_amdgcn_readfirstlane(n);   // wave-uniform -> s_loads of the feature row
    const float* r0 = f0 + (size_t)n * 256;
    float a0 = bm0[d];
#pragma unroll 8
    for (int k = 0; k < 256; ++k) a0 = fmaf(r0[k], Wm0[k * 64 + d], a0);
    hT0[(size_t)d * NODES + n] = f2bf(tanhf(a0));
    const float* r1 = f1 + (size_t)n * 128;
    float a1 = bm1[d];
#pragma unroll 8
    for (int k = 0; k < 128; ++k) a1 = fmaf(r1[k], Wm1[k * 64 + d], a1);
    hT1[(size_t)d * NODES + n] = f2bf(tanhf(a1));
}

// ---- adjacency GEMM, hT-staged tiled version -----------------------------
// Block = 64 rows x 64 feats x K-range. 4 waves, wave w owns rows wid*16..+16,
// acc persists across k-chunks (no k-split inside block). hT chunk (64d x 256k
// bf16 = 32 KB) double-buffered in LDS via global_load_lds with PRE-SWIZZLED
// global source (linear LDS dest, byte ^= (d&7)<<4 within 512B row) so
// ds_read_b128 B-frags are ~conflict-free. hT traffic per block = 512 KB total
// (vs 512 KB *per 16-row block* before: 4x reduction in redundant B reads).
__global__ __launch_bounds__(256, 2) void adj_gemm(
    const float* __restrict__ A0, const float* __restrict__ A1,
    const float* __restrict__ A2, const float* __restrict__ A3,
    const float* __restrict__ A4,
    const unsigned short* __restrict__ hTa, const unsigned short* __restrict__ hTb,
    int split, float* __restrict__ outBase, unsigned tanhMask,
    int khBits, int klen)
{
    __shared__ unsigned short sB[2][64][256];   // 2 x 32 KB

    const int job = blockIdx.y;
    const float* adj = job == 0 ? A0 : job == 1 ? A1 : job == 2 ? A2 : job == 3 ? A3 : A4;
    const unsigned short* hT = (job < split) ? hTa : hTb;
    const bool doTanh = (tanhMask >> job) & 1u;

    const int bx = blockIdx.x;
    const int group = bx >> khBits;
    const int kh = bx & ((1 << khBits) - 1);
    const int kc0 = kh * klen;
    const int nchunks = klen >> 8;
    const int n0 = group * 64;

    const int lane = threadIdx.x & 63;
    const int wid = threadIdx.x >> 6;
    const int fr = lane & 15, fg = lane >> 4;

    const char* hB = (const char*)hT;
    char* ldsBase = (char*)&sB[0][0][0];

    // per-lane glds source precompute: lane l of seg -> dest byte seg*1024+l*16
    const int gd_half = lane >> 5;               // +1 row for lanes 32..63
    const int gd_kb = (lane & 31) * 16;          // k-byte within 512B row

    const char* aPtr = (const char*)adj +
        ((size_t)(n0 + wid * 16 + fr) * NODES + kc0 + fg * 8) * 4;

    f32x4 acc0 = {0.f,0.f,0.f,0.f}, acc1 = {0.f,0.f,0.f,0.f};
    f32x4 acc2 = {0.f,0.f,0.f,0.f}, acc3 = {0.f,0.f,0.f,0.f};

    // ---- stage chunk 0 ----
    {
        const size_t cbyte = (size_t)kc0 * 2;
#pragma unroll
        for (int i = 0; i < 8; ++i) {
            const int seg = wid * 8 + i;
            char* ldst = ldsBase + seg * 1024;
            const int d = seg * 2 + gd_half;
            const int sb = gd_kb ^ ((d & 7) << 4);
            glds16(hB + (size_t)d * (NODES * 2) + cbyte + sb, ldst);
        }
    }
    __syncthreads();

    int cur = 0;
    for (int c = 0; c < nchunks; ++c) {
        if (c + 1 < nchunks) {              // stage next chunk into other buffer
            const size_t cbyte = (size_t)(kc0 + ((c + 1) << 8)) * 2;
            const int bufoff = (cur ^ 1) * 32768;
#pragma unroll
            for (int i = 0; i < 8; ++i) {
                const int seg = wid * 8 + i;
                char* ldst = ldsBase + bufoff + seg * 1024;
                const int d = seg * 2 + gd_half;
                const int sb = gd_kb ^ ((d & 7) << 4);
                glds16(hB + (size_t)d * (NODES * 2) + cbyte + sb, ldst);
            }
        }
        const char* bb = ldsBase + cur * 32768;
        const char* aC = aPtr + ((size_t)c << 10);
#pragma unroll
        for (int ks = 0; ks < 8; ++ks) {
            f32x8 av = *(const f32x8*)(aC + (ks << 7));
            bf16x8 af = __builtin_convertvector(av, bf16x8);
            {
                const int dcol = 0 * 16 + fr;
                const int off = dcol * 512 + (((ks << 6) + (fg << 4)) ^ ((dcol & 7) << 4));
                u16x8 bf = *(const u16x8*)(bb + off);
                acc0 = __builtin_amdgcn_mfma_f32_16x16x32_bf16(af, __builtin_bit_cast(bf16x8, bf), acc0, 0, 0, 0);
            }
            {
                const int dcol = 1 * 16 + fr;
                const int off = dcol * 512 + (((ks << 6) + (fg << 4)) ^ ((dcol & 7) << 4));
                u16x8 bf = *(const u16x8*)(bb + off);
                acc1 = __builtin_amdgcn_mfma_f32_16x16x32_bf16(af, __builtin_bit_cast(bf16x8, bf), acc1, 0, 0, 0);
            }
            {
                const int dcol = 2 * 16 + fr;
                const int off = dcol * 512 + (((ks << 6) + (fg << 4)) ^ ((dcol & 7) << 4));
                u16x8 bf = *(const u16x8*)(bb + off);
                acc2 = __builtin_amdgcn_mfma_f32_16x16x32_bf16(af, __builtin_bit_cast(bf16x8, bf), acc2, 0, 0, 0);
            }
            {
                const int dcol = 3 * 16 + fr;
                const int off = dcol * 512 + (((ks << 6) + (fg << 4)) ^ ((dcol & 7) << 4));
                u16x8 bf = *(const u16x8*)(bb + off);
                acc3 = __builtin_amdgcn_mfma_f32_16x16x32_bf16(af, __builtin_bit_cast(bf16x8, bf), acc3, 0, 0, 0);
            }
        }
        __syncthreads();
        cur ^= 1;
    }

    // C/D layout (verified): col = lane&15, row = (lane>>4)*4 + j
    float* outC = outBase + (size_t)((job << khBits) | kh) * (NODES * 64);
    float* Cw = outC + (size_t)(n0 + wid * 16 + fg * 4) * 64 + fr;
#pragma unroll
    for (int j = 0; j < 4; ++j) {
        float v0 = acc0[j], v1 = acc1[j], v2 = acc2[j], v3 = acc3[j];
        if (doTanh) { v0 = tanhf(v0); v1 = tanhf(v1); v2 = tanhf(v2); v3 = tanhf(v3); }
        Cw[(size_t)j * 64 + 0]  = v0; Cw[(size_t)j * 64 + 16] = v1;
        Cw[(size_t)j * 64 + 32] = v2; Cw[(size_t)j * 64 + 48] = v3;
    }
}

// ---- stage C: semantic-attention logits (atomic) + schema softmax -> iccT bf16 [64][4096]
__global__ __launch_bounds__(128) void stage_c(
    const float* __restrict__ agg, const float* __restrict__ Wa,
    const float* __restrict__ ba, const float* __restrict__ qa,
    const float* __restrict__ wsv, float* __restrict__ sacc,
    unsigned short* __restrict__ iccT)
{
    const int n = blockIdx.x;
    const int p = threadIdx.x;          // 0..127 = PROJ lanes
    __shared__ float rs[3][2];
    __shared__ float ru[2][2];

    const float* h0p = agg + (size_t)n * 64;                       // hr[0]
    const float* h1p = agg + ((size_t)NODES + n) * 64;             // hr[1]
    const float* h2p = agg + ((size_t)2 * NODES + n) * 64;         // hr[2]
    float a0 = ba[p], a1 = a0, a2 = a0;
#pragma unroll 8
    for (int d = 0; d < 64; ++d) {
        float w = Wa[d * 128 + p];
        a0 = fmaf(h0p[d], w, a0);
        a1 = fmaf(h1p[d], w, a1);
        a2 = fmaf(h2p[d], w, a2);
    }
    float qv = qa[p];
    float v0 = tanhf(a0) * qv, v1 = tanhf(a1) * qv, v2 = tanhf(a2) * qv;

    const float* z0 = agg + ((size_t)3 * NODES + n) * 64;          // zk[0]
    const float* z1 = agg + ((size_t)4 * NODES + n) * 64;          // zk[1]
    float u0 = (p < 64) ? z0[p] * wsv[p] : 0.f;
    float u1 = (p < 64) ? z1[p] * wsv[p] : 0.f;

#pragma unroll
    for (int off = 32; off; off >>= 1) {
        v0 += __shfl_down(v0, off); v1 += __shfl_down(v1, off); v2 += __shfl_down(v2, off);
        u0 += __shfl_down(u0, off); u1 += __shfl_down(u1, off);
    }
    if ((p & 63) == 0) {
        int w = p >> 6;
        rs[0][w] = v0; rs[1][w] = v1; rs[2][w] = v2;
        ru[0][w] = u0; ru[1][w] = u1;
    }
    __syncthreads();
    if (p < 3) atomicAdd(&sacc[p], rs[p][0] + rs[p][1]);

    float U0 = ru[0][0] + ru[0][1];
    float U1 = ru[1][0] + ru[1][1];
    float mx = fmaxf(U0, U1);
    float e0 = expf(U0 - mx), e1 = expf(U1 - mx);
    float inv = 1.f / (e0 + e1);
    if (p < 64) {
        float icc = (e0 * z0[p] + e1 * z1[p]) * inv;
        iccT[(size_t)p * NODES + n] = f2bf(icc);
    }
}

// ---- stage E: relation_agg, item-item attention, AggAttention, projection ----
// ymp holds 4 partial sums: [job0 kh0][job0 kh1][job1 kh0][job1 kh1]; we do
// ym[m] = tanh(partial_a + partial_b) here.
__global__ __launch_bounds__(256) void finalize(
    const float* __restrict__ agg, const float* __restrict__ ymp,
    const float* __restrict__ sacc,
    const float* __restrict__ Wc1, const float* __restrict__ bc1, const float* __restrict__ wc2,
    const float* __restrict__ Wt1, const float* __restrict__ bt1, const float* __restrict__ wt2,
    const float* __restrict__ Wp, const float* __restrict__ bp,
    float* __restrict__ out)
{
    __shared__ float sWc[64 * 128];
    __shared__ float sWp[64 * 16];
    __shared__ float sY0[2][64], sY1[2][64];
    __shared__ float sHs0[2][64], sHs1[2][64], sHv[2][64];
    __shared__ float rA[2][2], rB[2][2];

    const int t = threadIdx.x;
    for (int i = t; i < 64 * 128; i += 256) sWc[i] = Wc1[i];
    for (int i = t; i < 64 * 16; i += 256) sWp[i] = Wp[i];

    float s0 = sacc[0] * (1.f / NODES), s1 = sacc[1] * (1.f / NODES), s2 = sacc[2] * (1.f / NODES);
    float sm = fmaxf(s0, fmaxf(s1, s2));
    float b0 = expf(s0 - sm), b1 = expf(s1 - sm), b2 = expf(s2 - sm);
    float bi = 1.f / (b0 + b1 + b2);
    b0 *= bi; b1 *= bi; b2 *= bi;

    const int sub = t >> 7;       // 2 nodes processed in parallel
    const int p = t & 127;
    const int wiH = p >> 6;
    const float bcv = bc1[p], wcv = wc2[p], btv = bt1[p], wtv = wt2[p];
    __syncthreads();

    for (int it = 0; it < 8; ++it) {
        const int n = blockIdx.x * 16 + it * 2 + sub;
        if (p < 64) {
            const size_t NN64 = (size_t)NODES * 64;
            float ya = ymp[(size_t)n * 64 + p]            + ymp[NN64 + (size_t)n * 64 + p];
            float yb = ymp[2 * NN64 + (size_t)n * 64 + p] + ymp[3 * NN64 + (size_t)n * 64 + p];
            sY0[sub][p] = tanhf(ya);
            sY1[sub][p] = tanhf(yb);
            sHs0[sub][p] = b0 * agg[(size_t)n * 64 + p]
                         + b1 * agg[((size_t)NODES + n) * 64 + p]
                         + b2 * agg[((size_t)2 * NODES + n) * 64 + p];
        }
        __syncthreads();
        float ac0 = bcv, ac1 = bcv;
#pragma unroll 8
        for (int d = 0; d < 64; ++d) {
            float w = sWc[d * 128 + p];
            ac0 = fmaf(sY0[sub][d], w, ac0);
            ac1 = fmaf(sY1[sub][d], w, ac1);
        }
        float v0 = tanhf(ac0) * wcv, v1 = tanhf(ac1) * wcv;
#pragma unroll
        for (int off = 32; off; off >>= 1) { v0 += __shfl_down(v0, off); v1 += __shfl_down(v1, off); }
        if ((p & 63) == 0) { rA[sub][wiH] = v0; rB[sub][wiH] = v1; }
        __syncthreads();
        float wm0 = rA[sub][0] + rA[sub][1];
        float wm1 = rB[sub][0] + rB[sub][1];
        float mm = fmaxf(wm0, wm1);
        float g0 = expf(wm0 - mm), g1 = expf(wm1 - mm);
        float gi = 1.f / (g0 + g1);
        g0 *= gi; g1 *= gi;
        if (p < 64) sHs1[sub][p] = g0 * sY0[sub][p] + g1 * sY1[sub][p];
        __syncthreads();

        float at0 = btv, at1 = btv;
#pragma unroll 8
        for (int d = 0; d < 64; ++d) {
            float w = Wt1[d * 128 + p];
            at0 = fmaf(sHs0[sub][d], w, at0);
            at1 = fmaf(sHs1[sub][d], w, at1);
        }
        float q0 = tanhf(at0) * wtv, q1 = tanhf(at1) * wtv;
#pragma unroll
        for (int off = 32; off; off >>= 1) { q0 += __shfl_down(q0, off); q1 += __shfl_down(q1, off); }
        if ((p & 63) == 0) { rA[sub][wiH] = q0; rB[sub][wiH] = q1; }
        __syncthreads();
        float t0 = rA[sub][0] + rA[sub][1];
        float t1 = rB[sub][0] + rB[sub][1];
        float tm = fmaxf(t0, t1);
        float c0 = expf(t0 - tm), c1 = expf(t1 - tm);
        float ci = 1.f / (c0 + c1);
        c0 *= ci; c1 *= ci;
        if (p < 64) {
            float H = c0 * sHs0[sub][p] + c1 * sHs1[sub][p];
            sHv[sub][p] = H;
            out[(size_t)NODES * 16 + (size_t)n * 64 + p] = H;
        }
        __syncthreads();
        if (p < 16) {
            float a = bp[p];
#pragma unroll 8
            for (int d = 0; d < 64; ++d) a = fmaf(sHv[sub][d], sWp[d * 16 + p], a);
            out[(size_t)n * 16 + p] = a;
        }
        __syncthreads();
    }
}

extern "C" void kernel_launch(void* const* d_in, const int* in_sizes, int n_in,
                              void* d_out, int out_size, void* d_ws, size_t ws_size,
                              hipStream_t stream)
{
    const float* f0   = (const float*)d_in[0];
    const float* f1   = (const float*)d_in[1];
    const float* adjS = (const float*)d_in[2];
    const float* adjM = (const float*)d_in[3];
    const float* adjK = (const float*)d_in[4];
    const float* Wm0  = (const float*)d_in[5];
    const float* bm0  = (const float*)d_in[6];
    const float* Wm1  = (const float*)d_in[7];
    const float* bm1  = (const float*)d_in[8];
    const float* Wa   = (const float*)d_in[9];
    const float* ba   = (const float*)d_in[10];
    const float* qa   = (const float*)d_in[11];
    const float* wsv  = (const float*)d_in[12];
    const float* Wc1  = (const float*)d_in[13];
    const float* bc1  = (const float*)d_in[14];
    const float* wc2  = (const float*)d_in[15];
    const float* Wt1  = (const float*)d_in[16];
    const float* bt1  = (const float*)d_in[17];
    const float* wt2  = (const float*)d_in[18];
    const float* Wp   = (const float*)d_in[19];
    const float* bpv  = (const float*)d_in[20];
    float* out = (float*)d_out;

    // workspace layout (bytes) — total 8,912,960 B:
    //   0        hT0   512 KB
    //   524288   hT1   512 KB
    //   1048576  iccT  512 KB
    //   1572864  agg   5 MB   (slots s0..s4, 1 MB each)
    //   4718592  ymp   4 MB
    //   8912896  sacc  64 B
    char* ws = (char*)d_ws;
    unsigned short* hT0  = (unsigned short*)(ws);
    unsigned short* hT1  = (unsigned short*)(ws + 524288);
    unsigned short* iccT = (unsigned short*)(ws + 1048576);
    float* agg           = (float*)(ws + 1572864);
    float* ymp           = (float*)(ws + 4718592);
    float* sacc          = (float*)(ws + 8912896);

    hipMemsetAsync(sacc, 0, 64, stream);
    prep_h<<<dim3(1024), dim3(256), 0, stream>>>(f0, f1, Wm0, bm0, Wm1, bm1, hT0, hT1);

    const size_t NNs = (size_t)NODES * NODES;
    // jobs: hr[0..2] = tanh(adj_meta[r] @ h0), zk[0..1] = adj_schema[k] @ h1
    // grid: 64 row-groups x 5 jobs = 320 blocks, full K per block, tanh fused.
    adj_gemm<<<dim3(64, 5), dim3(256), 0, stream>>>(
        adjM, adjM + NNs, adjM + 2 * NNs, adjK, adjK + NNs,
        hT0, hT1, 3, agg, 0x7u, 0, 4096);
    stage_c<<<dim3(4096), dim3(128), 0, stream>>>(agg, Wa, ba, qa, wsv, sacc, iccT);
    // ym partials: 64 groups x 2 k-halves x 2 jobs = 256 blocks (1/CU), no tanh.
    adj_gemm<<<dim3(128, 2), dim3(256), 0, stream>>>(
        adjS, adjS + NNs, adjS, adjS, adjS,
        iccT, iccT, 5, ymp, 0x0u, 1, 2048);
    finalize<<<dim3(256), dim3(256), 0, stream>>>(
        agg, ymp, sacc, Wc1, bc1, wc2, Wt1, bt1, wt2, Wp, bpv, out);
}

// Round 4
// 256.053 us; speedup vs baseline: 1.2630x; 1.1680x over previous
//
#include <hip/hip_runtime.h>

#define NODES 4096

typedef float f32x4 __attribute__((ext_vector_type(4)));
typedef float f32x8 __attribute__((ext_vector_type(8)));
typedef __bf16 bf16x8 __attribute__((ext_vector_type(8)));
typedef unsigned short u16x8 __attribute__((ext_vector_type(8)));

__device__ __forceinline__ unsigned short f2bf(float x) {
    unsigned u = __builtin_bit_cast(unsigned, x);
    return (unsigned short)((u + 0x7fffu + ((u >> 16) & 1u)) >> 16);
}

__device__ __forceinline__ void glds16(const void* g, void* l) {
    __builtin_amdgcn_global_load_lds(
        (const __attribute__((address_space(1))) unsigned int*)g,
        (__attribute__((address_space(3))) unsigned int*)l,
        16, 0, 0);
}

// ---- stage A: h = tanh(x@Wm + bm), stored transposed bf16 [64][4096] -------
__global__ __launch_bounds__(256) void prep_h(
    const float* __restrict__ f0, const float* __restrict__ f1,
    const float* __restrict__ Wm0, const float* __restrict__ bm0,
    const float* __restrict__ Wm1, const float* __restrict__ bm1,
    unsigned short* __restrict__ hT0, unsigned short* __restrict__ hT1)
{
    const int d = threadIdx.x & 63;
    int n = blockIdx.x * 4 + (threadIdx.x >> 6);
    n = __builtin_amdgcn_readfirstlane(n);   // wave-uniform -> s_loads of the feature row
    const float* r0 = f0 + (size_t)n * 256;
    float a0 = bm0[d];
#pragma unroll 8
    for (int k = 0; k < 256; ++k) a0 = fmaf(r0[k], Wm0[k * 64 + d], a0);
    hT0[(size_t)d * NODES + n] = f2bf(tanhf(a0));
    const float* r1 = f1 + (size_t)n * 128;
    float a1 = bm1[d];
#pragma unroll 8
    for (int k = 0; k < 128; ++k) a1 = fmaf(r1[k], Wm1[k * 64 + d], a1);
    hT1[(size_t)d * NODES + n] = f2bf(tanhf(a1));
}

// ---- adjacency GEMM: counted-vmcnt glds pipeline (T3/T4 minimum template) --
// Block = 64 rows x 64 cols; wave w owns rows w*16..+16. Chunk = 128 k.
// Per chunk per wave: 8 glds (A f32 32KB/block) + 4 glds (B bf16 16KB/block),
// all via global_load_lds (no dest reg -> compiler can't sink). Double buffer,
// raw s_barrier + asm s_waitcnt vmcnt(12): next chunk always in flight.
// Swizzle (both-sides involution, rule #21): byte ^= (row&7)<<4, applied to
// glds SOURCE (dest linear) and to ds_read address.
__global__ __launch_bounds__(256) void adj_gemm(
    const float* __restrict__ A0, const float* __restrict__ A1,
    const float* __restrict__ A2, const float* __restrict__ A3,
    const float* __restrict__ A4,
    const unsigned short* __restrict__ hTa, const unsigned short* __restrict__ hTb,
    int split, float* __restrict__ outBase, unsigned tanhMask,
    int khBits, int klen)
{
    __shared__ __align__(16) char smem[2 * 49152];   // [buf][A 32KB][B 16KB]

    const int job = blockIdx.y;
    const float* adj = job == 0 ? A0 : job == 1 ? A1 : job == 2 ? A2 : job == 3 ? A3 : A4;
    const unsigned short* hT = (job < split) ? hTa : hTb;
    const bool doTanh = (tanhMask >> job) & 1u;

    const int bx = blockIdx.x;
    const int group = bx >> khBits;
    const int kh = bx & ((1 << khBits) - 1);
    const int kc0 = kh * klen;          // element offset of this K-slice
    const int nc = klen >> 7;           // chunks of 128 k
    const int n0 = group * 64;

    const int lane = threadIdx.x & 63;
    const int wid = threadIdx.x >> 6;
    const int fr = lane & 15, fg = lane >> 4;

    // ---- staging address setup (all compile-time-unrolled, rule #20) ----
    const char* aBase = (const char*)adj;
    const char* hBase = (const char*)hT;
    const char* aSrc[8]; int aDst[8];
#pragma unroll
    for (int i = 0; i < 8; ++i) {
        const int seg = wid * 8 + i;                 // 1 KB seg = 2 rows x 512 B
        const int rowc = seg * 2 + (lane >> 5);
        const int kbs = (lane & 31) * 16;
        const int kb = kbs ^ ((rowc & 7) << 4);      // source pre-swizzle
        aSrc[i] = aBase + (size_t)(n0 + rowc) * (NODES * 4) + (size_t)kc0 * 4 + kb;
        aDst[i] = seg * 1024;
    }
    const char* bSrc[4]; int bDst[4];
#pragma unroll
    for (int i = 0; i < 4; ++i) {
        const int seg = wid * 4 + i;                 // 1 KB seg = 4 rows x 256 B
        const int d = seg * 4 + (lane >> 4);
        const int kbs = (lane & 15) * 16;
        const int kb = kbs ^ ((d & 7) << 4);
        bSrc[i] = hBase + (size_t)d * (NODES * 2) + (size_t)kc0 * 2 + kb;
        bDst[i] = 32768 + seg * 1024;
    }

#define STAGE(c)                                                          \
    {                                                                     \
        char* dstb = smem + ((c) & 1) * 49152;                            \
        const size_t aoff = (size_t)(c) * 512;                            \
        const size_t boff = (size_t)(c) * 256;                            \
        _Pragma("unroll")                                                 \
        for (int i = 0; i < 8; ++i) glds16(aSrc[i] + aoff, dstb + aDst[i]); \
        _Pragma("unroll")                                                 \
        for (int i = 0; i < 4; ++i) glds16(bSrc[i] + boff, dstb + bDst[i]); \
    }

    f32x4 acc0 = {0.f,0.f,0.f,0.f}, acc1 = {0.f,0.f,0.f,0.f};
    f32x4 acc2 = {0.f,0.f,0.f,0.f}, acc3 = {0.f,0.f,0.f,0.f};

    const int rowA = wid * 16 + fr;
    const int swzA = (rowA & 7) << 4;

    STAGE(0);
    STAGE(1);

    for (int c = 0; c < nc; ++c) {
        if (c + 1 < nc) { asm volatile("s_waitcnt vmcnt(12)" ::: "memory"); }
        else            { asm volatile("s_waitcnt vmcnt(0)"  ::: "memory"); }
        __builtin_amdgcn_sched_barrier(0);
        __builtin_amdgcn_s_barrier();
        __builtin_amdgcn_sched_barrier(0);

        const char* bb = smem + (c & 1) * 49152;
        const char* aRow = bb + rowA * 512;
#pragma unroll
        for (int ks = 0; ks < 4; ++ks) {
            const int kb = ks * 128 + fg * 32;
            f32x4 alo = *(const f32x4*)(aRow + ((kb)      ^ swzA));
            f32x4 ahi = *(const f32x4*)(aRow + ((kb + 16) ^ swzA));
            f32x8 av = __builtin_shufflevector(alo, ahi, 0,1,2,3,4,5,6,7);
            bf16x8 af = __builtin_convertvector(av, bf16x8);
            const int kb2 = ks * 64 + fg * 16;
            {
                const int dcol = 0 * 16 + fr;
                u16x8 bv = *(const u16x8*)(bb + 32768 + dcol * 256 + (kb2 ^ ((dcol & 7) << 4)));
                acc0 = __builtin_amdgcn_mfma_f32_16x16x32_bf16(af, __builtin_bit_cast(bf16x8, bv), acc0, 0, 0, 0);
            }
            {
                const int dcol = 1 * 16 + fr;
                u16x8 bv = *(const u16x8*)(bb + 32768 + dcol * 256 + (kb2 ^ ((dcol & 7) << 4)));
                acc1 = __builtin_amdgcn_mfma_f32_16x16x32_bf16(af, __builtin_bit_cast(bf16x8, bv), acc1, 0, 0, 0);
            }
            {
                const int dcol = 2 * 16 + fr;
                u16x8 bv = *(const u16x8*)(bb + 32768 + dcol * 256 + (kb2 ^ ((dcol & 7) << 4)));
                acc2 = __builtin_amdgcn_mfma_f32_16x16x32_bf16(af, __builtin_bit_cast(bf16x8, bv), acc2, 0, 0, 0);
            }
            {
                const int dcol = 3 * 16 + fr;
                u16x8 bv = *(const u16x8*)(bb + 32768 + dcol * 256 + (kb2 ^ ((dcol & 7) << 4)));
                acc3 = __builtin_amdgcn_mfma_f32_16x16x32_bf16(af, __builtin_bit_cast(bf16x8, bv), acc3, 0, 0, 0);
            }
        }

        __builtin_amdgcn_sched_barrier(0);
        __builtin_amdgcn_s_barrier();
        __builtin_amdgcn_sched_barrier(0);
        if (c + 2 < nc) STAGE(c + 2);
    }
#undef STAGE

    // C/D layout (verified): col = lane&15, row = (lane>>4)*4 + j
    float* outC = outBase + (size_t)((job << khBits) | kh) * (NODES * 64);
    float* Cw = outC + (size_t)(n0 + wid * 16 + fg * 4) * 64 + fr;
#pragma unroll
    for (int j = 0; j < 4; ++j) {
        float v0 = acc0[j], v1 = acc1[j], v2 = acc2[j], v3 = acc3[j];
        if (doTanh) { v0 = tanhf(v0); v1 = tanhf(v1); v2 = tanhf(v2); v3 = tanhf(v3); }
        Cw[(size_t)j * 64 + 0]  = v0; Cw[(size_t)j * 64 + 16] = v1;
        Cw[(size_t)j * 64 + 32] = v2; Cw[(size_t)j * 64 + 48] = v3;
    }
}

// ---- stage C: semantic-attention logits (atomic) + schema softmax -> iccT bf16 [64][4096]
__global__ __launch_bounds__(128) void stage_c(
    const float* __restrict__ agg, const float* __restrict__ Wa,
    const float* __restrict__ ba, const float* __restrict__ qa,
    const float* __restrict__ wsv, float* __restrict__ sacc,
    unsigned short* __restrict__ iccT)
{
    const int n = blockIdx.x;
    const int p = threadIdx.x;          // 0..127 = PROJ lanes
    __shared__ float rs[3][2];
    __shared__ float ru[2][2];

    const float* h0p = agg + (size_t)n * 64;                       // hr[0]
    const float* h1p = agg + ((size_t)NODES + n) * 64;             // hr[1]
    const float* h2p = agg + ((size_t)2 * NODES + n) * 64;         // hr[2]
    float a0 = ba[p], a1 = a0, a2 = a0;
#pragma unroll 8
    for (int d = 0; d < 64; ++d) {
        float w = Wa[d * 128 + p];
        a0 = fmaf(h0p[d], w, a0);
        a1 = fmaf(h1p[d], w, a1);
        a2 = fmaf(h2p[d], w, a2);
    }
    float qv = qa[p];
    float v0 = tanhf(a0) * qv, v1 = tanhf(a1) * qv, v2 = tanhf(a2) * qv;

    const float* z0 = agg + ((size_t)3 * NODES + n) * 64;          // zk[0]
    const float* z1 = agg + ((size_t)4 * NODES + n) * 64;          // zk[1]
    float u0 = (p < 64) ? z0[p] * wsv[p] : 0.f;
    float u1 = (p < 64) ? z1[p] * wsv[p] : 0.f;

#pragma unroll
    for (int off = 32; off; off >>= 1) {
        v0 += __shfl_down(v0, off); v1 += __shfl_down(v1, off); v2 += __shfl_down(v2, off);
        u0 += __shfl_down(u0, off); u1 += __shfl_down(u1, off);
    }
    if ((p & 63) == 0) {
        int w = p >> 6;
        rs[0][w] = v0; rs[1][w] = v1; rs[2][w] = v2;
        ru[0][w] = u0; ru[1][w] = u1;
    }
    __syncthreads();
    if (p < 3) atomicAdd(&sacc[p], rs[p][0] + rs[p][1]);

    float U0 = ru[0][0] + ru[0][1];
    float U1 = ru[1][0] + ru[1][1];
    float mx = fmaxf(U0, U1);
    float e0 = expf(U0 - mx), e1 = expf(U1 - mx);
    float inv = 1.f / (e0 + e1);
    if (p < 64) {
        float icc = (e0 * z0[p] + e1 * z1[p]) * inv;
        iccT[(size_t)p * NODES + n] = f2bf(icc);
    }
}

// ---- stage E: relation_agg, item-item attention, AggAttention, projection ----
// ymp holds 4 partial sums: [job0 kh0][job0 kh1][job1 kh0][job1 kh1]; we do
// ym[m] = tanh(partial_a + partial_b) here.
__global__ __launch_bounds__(256) void finalize(
    const float* __restrict__ agg, const float* __restrict__ ymp,
    const float* __restrict__ sacc,
    const float* __restrict__ Wc1, const float* __restrict__ bc1, const float* __restrict__ wc2,
    const float* __restrict__ Wt1, const float* __restrict__ bt1, const float* __restrict__ wt2,
    const float* __restrict__ Wp, const float* __restrict__ bp,
    float* __restrict__ out)
{
    __shared__ float sWc[64 * 128];
    __shared__ float sWp[64 * 16];
    __shared__ float sY0[2][64], sY1[2][64];
    __shared__ float sHs0[2][64], sHs1[2][64], sHv[2][64];
    __shared__ float rA[2][2], rB[2][2];

    const int t = threadIdx.x;
    for (int i = t; i < 64 * 128; i += 256) sWc[i] = Wc1[i];
    for (int i = t; i < 64 * 16; i += 256) sWp[i] = Wp[i];

    float s0 = sacc[0] * (1.f / NODES), s1 = sacc[1] * (1.f / NODES), s2 = sacc[2] * (1.f / NODES);
    float sm = fmaxf(s0, fmaxf(s1, s2));
    float b0 = expf(s0 - sm), b1 = expf(s1 - sm), b2 = expf(s2 - sm);
    float bi = 1.f / (b0 + b1 + b2);
    b0 *= bi; b1 *= bi; b2 *= bi;

    const int sub = t >> 7;       // 2 nodes processed in parallel
    const int p = t & 127;
    const int wiH = p >> 6;
    const float bcv = bc1[p], wcv = wc2[p], btv = bt1[p], wtv = wt2[p];
    __syncthreads();

    for (int it = 0; it < 8; ++it) {
        const int n = blockIdx.x * 16 + it * 2 + sub;
        if (p < 64) {
            const size_t NN64 = (size_t)NODES * 64;
            float ya = ymp[(size_t)n * 64 + p]            + ymp[NN64 + (size_t)n * 64 + p];
            float yb = ymp[2 * NN64 + (size_t)n * 64 + p] + ymp[3 * NN64 + (size_t)n * 64 + p];
            sY0[sub][p] = tanhf(ya);
            sY1[sub][p] = tanhf(yb);
            sHs0[sub][p] = b0 * agg[(size_t)n * 64 + p]
                         + b1 * agg[((size_t)NODES + n) * 64 + p]
                         + b2 * agg[((size_t)2 * NODES + n) * 64 + p];
        }
        __syncthreads();
        float ac0 = bcv, ac1 = bcv;
#pragma unroll 8
        for (int d = 0; d < 64; ++d) {
            float w = sWc[d * 128 + p];
            ac0 = fmaf(sY0[sub][d], w, ac0);
            ac1 = fmaf(sY1[sub][d], w, ac1);
        }
        float v0 = tanhf(ac0) * wcv, v1 = tanhf(ac1) * wcv;
#pragma unroll
        for (int off = 32; off; off >>= 1) { v0 += __shfl_down(v0, off); v1 += __shfl_down(v1, off); }
        if ((p & 63) == 0) { rA[sub][wiH] = v0; rB[sub][wiH] = v1; }
        __syncthreads();
        float wm0 = rA[sub][0] + rA[sub][1];
        float wm1 = rB[sub][0] + rB[sub][1];
        float mm = fmaxf(wm0, wm1);
        float g0 = expf(wm0 - mm), g1 = expf(wm1 - mm);
        float gi = 1.f / (g0 + g1);
        g0 *= gi; g1 *= gi;
        if (p < 64) sHs1[sub][p] = g0 * sY0[sub][p] + g1 * sY1[sub][p];
        __syncthreads();

        float at0 = btv, at1 = btv;
#pragma unroll 8
        for (int d = 0; d < 64; ++d) {
            float w = Wt1[d * 128 + p];
            at0 = fmaf(sHs0[sub][d], w, at0);
            at1 = fmaf(sHs1[sub][d], w, at1);
        }
        float q0 = tanhf(at0) * wtv, q1 = tanhf(at1) * wtv;
#pragma unroll
        for (int off = 32; off; off >>= 1) { q0 += __shfl_down(q0, off); q1 += __shfl_down(q1, off); }
        if ((p & 63) == 0) { rA[sub][wiH] = q0; rB[sub][wiH] = q1; }
        __syncthreads();
        float t0 = rA[sub][0] + rA[sub][1];
        float t1 = rB[sub][0] + rB[sub][1];
        float tm = fmaxf(t0, t1);
        float c0 = expf(t0 - tm), c1 = expf(t1 - tm);
        float ci = 1.f / (c0 + c1);
        c0 *= ci; c1 *= ci;
        if (p < 64) {
            float H = c0 * sHs0[sub][p] + c1 * sHs1[sub][p];
            sHv[sub][p] = H;
            out[(size_t)NODES * 16 + (size_t)n * 64 + p] = H;
        }
        __syncthreads();
        if (p < 16) {
            float a = bp[p];
#pragma unroll 8
            for (int d = 0; d < 64; ++d) a = fmaf(sHv[sub][d], sWp[d * 16 + p], a);
            out[(size_t)n * 16 + p] = a;
        }
        __syncthreads();
    }
}

extern "C" void kernel_launch(void* const* d_in, const int* in_sizes, int n_in,
                              void* d_out, int out_size, void* d_ws, size_t ws_size,
                              hipStream_t stream)
{
    const float* f0   = (const float*)d_in[0];
    const float* f1   = (const float*)d_in[1];
    const float* adjS = (const float*)d_in[2];
    const float* adjM = (const float*)d_in[3];
    const float* adjK = (const float*)d_in[4];
    const float* Wm0  = (const float*)d_in[5];
    const float* bm0  = (const float*)d_in[6];
    const float* Wm1  = (const float*)d_in[7];
    const float* bm1  = (const float*)d_in[8];
    const float* Wa   = (const float*)d_in[9];
    const float* ba   = (const float*)d_in[10];
    const float* qa   = (const float*)d_in[11];
    const float* wsv  = (const float*)d_in[12];
    const float* Wc1  = (const float*)d_in[13];
    const float* bc1  = (const float*)d_in[14];
    const float* wc2  = (const float*)d_in[15];
    const float* Wt1  = (const float*)d_in[16];
    const float* bt1  = (const float*)d_in[17];
    const float* wt2  = (const float*)d_in[18];
    const float* Wp   = (const float*)d_in[19];
    const float* bpv  = (const float*)d_in[20];
    float* out = (float*)d_out;

    // workspace layout (bytes) — total 8,912,960 B:
    //   0        hT0   512 KB
    //   524288   hT1   512 KB
    //   1048576  iccT  512 KB
    //   1572864  agg   5 MB   (slots s0..s4, 1 MB each)
    //   4718592  ymp   4 MB
    //   8912896  sacc  64 B
    char* ws = (char*)d_ws;
    unsigned short* hT0  = (unsigned short*)(ws);
    unsigned short* hT1  = (unsigned short*)(ws + 524288);
    unsigned short* iccT = (unsigned short*)(ws + 1048576);
    float* agg           = (float*)(ws + 1572864);
    float* ymp           = (float*)(ws + 4718592);
    float* sacc          = (float*)(ws + 8912896);

    hipMemsetAsync(sacc, 0, 64, stream);
    prep_h<<<dim3(1024), dim3(256), 0, stream>>>(f0, f1, Wm0, bm0, Wm1, bm1, hT0, hT1);

    const size_t NNs = (size_t)NODES * NODES;
    // jobs: hr[0..2] = tanh(adj_meta[r] @ h0), zk[0..1] = adj_schema[k] @ h1
    // grid: 64 row-groups x 5 jobs = 320 blocks, full K per block, tanh fused.
    adj_gemm<<<dim3(64, 5), dim3(256), 0, stream>>>(
        adjM, adjM + NNs, adjM + 2 * NNs, adjK, adjK + NNs,
        hT0, hT1, 3, agg, 0x7u, 0, 4096);
    stage_c<<<dim3(4096), dim3(128), 0, stream>>>(agg, Wa, ba, qa, wsv, sacc, iccT);
    // ym partials: 64 groups x 2 k-halves x 2 jobs = 256 blocks (1/CU), no tanh.
    adj_gemm<<<dim3(128, 2), dim3(256), 0, stream>>>(
        adjS, adjS + NNs, adjS, adjS, adjS,
        iccT, iccT, 5, ymp, 0x0u, 1, 2048);
    finalize<<<dim3(256), dim3(256), 0, stream>>>(
        agg, ymp, sacc, Wc1, bc1, wc2, Wt1, bt1, wt2, Wp, bpv, out);
}